// Round 10
// baseline (242.666 us; speedup 1.0000x reference)
//
#include <hip/hip_runtime.h>
#include <hip/hip_bf16.h>
#include <stdint.h>

// Problem constants
#define D_MODEL 1024
#define BATCH   4
#define SEQ     4096
#define M_TOTAL (BATCH*SEQ)   // 16384
#define KDIM    1024
#define NTOT    2048          // combined N (z cols 0..1023, h cols 1024..2047)

// Scan chunking
#define NCH 128               // chunks per batch
#define CL (SEQ/NCH)          // 32

// GEMM tiling: round-2 structure VERBATIM (best measured: 96.5us, 712 TF)
#define BM 256
#define BN 256
#define BK 32
#define NT (KDIM/BK)          // 32 K-tiles

typedef __bf16 bf16x8 __attribute__((ext_vector_type(8)));
typedef float  f32x4  __attribute__((ext_vector_type(4)));
typedef unsigned short u16x4 __attribute__((ext_vector_type(4)));

static __device__ __forceinline__ unsigned short f2bf(float f) {
  unsigned u = __builtin_bit_cast(unsigned, f);
  u += 0x7FFFu + ((u >> 16) & 1u);     // round-to-nearest-even
  return (unsigned short)(u >> 16);
}
static __device__ __forceinline__ float bf2f(unsigned short u) {
  return __builtin_bit_cast(float, (unsigned)u << 16);
}

// ---------------- K0a: x (fp32) -> bf16 ----------------
__global__ __launch_bounds__(256) void k_cvt_x(const float* __restrict__ x,
                                               unsigned short* __restrict__ xb) {
  int i = blockIdx.x * 256 + threadIdx.x;          // 4 elems each
  float4 v = ((const float4*)x)[i];
  ushort4 o;
  o.x = f2bf(v.x); o.y = f2bf(v.y); o.z = f2bf(v.z); o.w = f2bf(v.w);
  ((ushort4*)xb)[i] = o;
}

// ---------------- K0b: W (fp32 [d][e]) -> bf16 transposed [e][d] ----------------
__global__ void k_cvt_wT(const float* __restrict__ Wz, const float* __restrict__ Wh,
                         unsigned short* __restrict__ WzT, unsigned short* __restrict__ WhT) {
  __shared__ float tile[32][33];
  const float* W = blockIdx.z ? Wh : Wz;
  unsigned short* O = blockIdx.z ? WhT : WzT;
  int bx = blockIdx.x * 32;   // e base
  int by = blockIdx.y * 32;   // d base
  int tx = threadIdx.x, ty = threadIdx.y; // 32 x 8
  for (int yy = ty; yy < 32; yy += 8)
    tile[yy][tx] = W[(size_t)(by + yy) * D_MODEL + bx + tx];
  __syncthreads();
  for (int yy = ty; yy < 32; yy += 8)
    O[(size_t)(bx + yy) * D_MODEL + by + tx] = f2bf(tile[tx][yy]);
}

// ---------------- K1: GEMM  [P|Q](bf16) = xb @ Wall^T — ROUND-2 VERBATIM --------
// Best measured GEMM this session (96.5us, 712 TF): 256x256 tile, BK=32,
// 8 waves (2Mx4N, 128x64 each), triple-buffered LDS, depth-2 prefetch,
// counted vmcnt(4) (never 0 until tail), raw barriers, frag-major
// conflict-free LDS, original mfma(a,b) operand order + scalar-store epilogue
// (R8 showed the "packed 8B" variant is 5us WORSE: row-scattered stores).
__global__ __launch_bounds__(512, 2) void k_gemm8(
    const unsigned short* __restrict__ xb,    // [M][K] bf16
    const unsigned short* __restrict__ Wall,  // [2048][K] bf16 ([WzT;WhT])
    unsigned short* __restrict__ P, unsigned short* __restrict__ Q)
{
  __shared__ __attribute__((aligned(16))) unsigned short lds[3 * 16384]; // 96 KB

  const int tid  = threadIdx.x;
  const int wave = tid >> 6;
  const int lane = tid & 63;
  const int m0 = blockIdx.x * BM;
  const int n0 = blockIdx.y * BN;
  const int wr = wave >> 2;            // 0..1  (128 rows each)
  const int wc = wave & 3;             // 0..3  (64 cols each)
  const int lr = lane & 15;

  const int p0 = wave * 2, p1 = wave * 2 + 1;
  const int c0 = p0 >> 2, rb0 = p0 & 3;
  const int c1 = p1 >> 2, rb1 = p1 & 3;

  f32x4 acc[8][4];
  #pragma unroll
  for (int i = 0; i < 8; ++i)
    #pragma unroll
    for (int j = 0; j < 4; ++j) acc[i][j] = (f32x4){0.f, 0.f, 0.f, 0.f};

  auto stage = [&](int kt, int bufb) {
    const int kb = kt * BK;
    unsigned short* ldsA = &lds[bufb * 16384];
    unsigned short* ldsB = ldsA + 8192;
    const unsigned short* a0 = xb   + (size_t)(m0 + rb0*64 + lane) * KDIM + kb + c0*8;
    const unsigned short* a1 = xb   + (size_t)(m0 + rb1*64 + lane) * KDIM + kb + c1*8;
    const unsigned short* b0 = Wall + (size_t)(n0 + rb0*64 + lane) * KDIM + kb + c0*8;
    const unsigned short* b1 = Wall + (size_t)(n0 + rb1*64 + lane) * KDIM + kb + c1*8;
    __builtin_amdgcn_global_load_lds((const __attribute__((address_space(1))) unsigned int*)a0,
        (__attribute__((address_space(3))) unsigned int*)(ldsA + (c0*256 + rb0*64)*8), 16, 0, 0);
    __builtin_amdgcn_global_load_lds((const __attribute__((address_space(1))) unsigned int*)a1,
        (__attribute__((address_space(3))) unsigned int*)(ldsA + (c1*256 + rb1*64)*8), 16, 0, 0);
    __builtin_amdgcn_global_load_lds((const __attribute__((address_space(1))) unsigned int*)b0,
        (__attribute__((address_space(3))) unsigned int*)(ldsB + (c0*256 + rb0*64)*8), 16, 0, 0);
    __builtin_amdgcn_global_load_lds((const __attribute__((address_space(1))) unsigned int*)b1,
        (__attribute__((address_space(3))) unsigned int*)(ldsB + (c1*256 + rb1*64)*8), 16, 0, 0);
  };

  stage(0, 0);
  stage(1, 1);
  asm volatile("s_waitcnt vmcnt(4)" ::: "memory");
  __builtin_amdgcn_s_barrier();

  const int lc  = lane >> 4;
  const int aoff = (lc * 256 + wr * 128 + lr) * 8;   // shorts
  const int boff = (lc * 256 + wc * 64  + lr) * 8;

  int buf = 0;
  for (int kt = 0; kt < NT; ++kt) {
    if (kt + 2 < NT) {
      int db = buf + 2; if (db >= 3) db -= 3;
      stage(kt + 2, db);
    }

    const unsigned short* bufA = &lds[buf * 16384];
    const unsigned short* bufB = bufA + 8192;

    bf16x8 bfrag[4];
    #pragma unroll
    for (int nf = 0; nf < 4; ++nf)
      bfrag[nf] = *(const bf16x8*)(bufB + boff + nf * 128);
    bf16x8 afrag[4];
    #pragma unroll
    for (int mf = 0; mf < 4; ++mf)
      afrag[mf] = *(const bf16x8*)(bufA + aoff + mf * 128);

    __builtin_amdgcn_s_setprio(1);
    #pragma unroll
    for (int mf = 0; mf < 4; ++mf)
      #pragma unroll
      for (int nf = 0; nf < 4; ++nf)
        acc[mf][nf] = __builtin_amdgcn_mfma_f32_16x16x32_bf16(afrag[mf], bfrag[nf], acc[mf][nf], 0, 0, 0);
    __builtin_amdgcn_s_setprio(0);

    #pragma unroll
    for (int mf = 0; mf < 4; ++mf)
      afrag[mf] = *(const bf16x8*)(bufA + aoff + (mf + 4) * 128);

    __builtin_amdgcn_s_setprio(1);
    #pragma unroll
    for (int mf = 0; mf < 4; ++mf)
      #pragma unroll
      for (int nf = 0; nf < 4; ++nf)
        acc[mf + 4][nf] = __builtin_amdgcn_mfma_f32_16x16x32_bf16(afrag[mf], bfrag[nf], acc[mf + 4][nf], 0, 0, 0);
    __builtin_amdgcn_s_setprio(0);

    if (kt < NT - 2) asm volatile("s_waitcnt vmcnt(4)" ::: "memory");
    else             asm volatile("s_waitcnt vmcnt(0)" ::: "memory");
    __builtin_amdgcn_s_barrier();
    buf = (buf == 2) ? 0 : buf + 1;
  }

  // epilogue: C/D layout col = lane&15 (within nf), row = 4*(lane>>4)+r (within mf)
  unsigned short* Cout = (n0 < 1024) ? P : Q;
  const int colb = (n0 < 1024) ? n0 : (n0 - 1024);
  const int cb = lane & 15;
  const int rb4 = (lane >> 4) * 4;
  #pragma unroll
  for (int mf = 0; mf < 8; ++mf) {
    #pragma unroll
    for (int nf = 0; nf < 4; ++nf) {
      const size_t col  = (size_t)(colb + wc * 64 + nf * 16 + cb);
      const size_t row0 = (size_t)(m0 + wr * 128 + mf * 16 + rb4);
      #pragma unroll
      for (int r = 0; r < 4; ++r)
        Cout[(row0 + r) * D_MODEL + col] = f2bf(acc[mf][nf][r]);
    }
  }
}

// ---------------- K2a: zero the lookback flags (graph-capture-safe) ------------
__global__ __launch_bounds__(256) void k_zero_flags(int* __restrict__ flags) {
  flags[threadIdx.x] = 0;
  flags[threadIdx.x + 256] = 0;
}

// ---------------- K2: single-pass fused scan (aggregate-only lookback) ---------
// One block per (b,c) chunk, 256 threads x 4 d. Pass 1: chunk aggregate (A,B)
// per d; publish + release-flag. Lookback: threads 0..c-1 spin (acquire) on
// predecessor flags, then fold ALL c aggregates (independent pipelined float4
// loads, no prefix chain -> no serial dependency). Pass 2: apply, re-reading
// own chunk (L2-resident) and writing fp32 h to out.
// Deterministic (values independent of timing); all 512 blocks co-resident.
__global__ __launch_bounds__(256) void k_scan_fused(
    const unsigned short* __restrict__ P, const unsigned short* __restrict__ Q,
    const float* __restrict__ bz, const float* __restrict__ bh,
    float* __restrict__ Aagg, float* __restrict__ Bagg,
    int* __restrict__ flags, float* __restrict__ out)
{
  const int c = blockIdx.x & (NCH - 1);
  const int b = blockIdx.x >> 7;
  const int d = threadIdx.x * 4;
  const f32x4 vbz = *(const f32x4*)(bz + d);
  const f32x4 vbh = *(const f32x4*)(bh + d);
  const size_t base = ((size_t)b * SEQ + (size_t)c * CL) * D_MODEL + d;

  // ---- pass 1: chunk aggregate ----
  f32x4 A = {1.f, 1.f, 1.f, 1.f}, Bv = {0.f, 0.f, 0.f, 0.f};
  for (int t = 0; t < CL; ++t) {
    u16x4 pu = *(const u16x4*)(P + base + (size_t)t * D_MODEL);
    u16x4 qu = *(const u16x4*)(Q + base + (size_t)t * D_MODEL);
    #pragma unroll
    for (int r = 0; r < 4; ++r) {
      float z = 1.f / (1.f + __expf(-(bf2f(pu[r]) + vbz[r])));
      float a = 1.f - z;
      Bv[r] = a * Bv[r] + z * (bf2f(qu[r]) + vbh[r]);
      A[r]  = a * A[r];
    }
  }
  const size_t o = ((size_t)b * NCH + c) * D_MODEL + d;
  *(f32x4*)(Aagg + o) = A;
  *(f32x4*)(Bagg + o) = Bv;
  __threadfence();                 // agent-scope: L2 writeback of the stores
  __syncthreads();                 // all 256 threads' stores drained
  if (threadIdx.x == 0)
    __hip_atomic_store(&flags[b * NCH + c], 1, __ATOMIC_RELEASE, __HIP_MEMORY_SCOPE_AGENT);

  // ---- lookback: wait for all predecessors, then fold aggregates ----
  f32x4 h = {0.f, 0.f, 0.f, 0.f};
  if (c > 0) {
    if ((int)threadIdx.x < c) {
      while (__hip_atomic_load(&flags[b * NCH + threadIdx.x],
                               __ATOMIC_ACQUIRE, __HIP_MEMORY_SCOPE_AGENT) == 0) {}
    }
    __syncthreads();
    f32x4 Ar = {1.f, 1.f, 1.f, 1.f};
    #pragma unroll 2
    for (int j = c - 1; j >= 0; --j) {
      const size_t oj = ((size_t)b * NCH + j) * D_MODEL + d;
      f32x4 Aj = *(const f32x4*)(Aagg + oj);
      f32x4 Bj = *(const f32x4*)(Bagg + oj);
      h  = Ar * Bj + h;            // compose: chunks j..c-1 applied to h0=0
      Ar = Ar * Aj;
    }
  }

  // ---- pass 2: apply (own chunk is L2-resident from pass 1) ----
  for (int t = 0; t < CL; ++t) {
    u16x4 pu = *(const u16x4*)(P + base + (size_t)t * D_MODEL);
    u16x4 qu = *(const u16x4*)(Q + base + (size_t)t * D_MODEL);
    #pragma unroll
    for (int r = 0; r < 4; ++r) {
      float z = 1.f / (1.f + __expf(-(bf2f(pu[r]) + vbz[r])));
      float a = 1.f - z;
      h[r] = a * h[r] + z * (bf2f(qu[r]) + vbh[r]);
    }
    *(f32x4*)(out + base + (size_t)t * D_MODEL) = h;
  }
}

extern "C" void kernel_launch(void* const* d_in, const int* in_sizes, int n_in,
                              void* d_out, int out_size, void* d_ws, size_t ws_size,
                              hipStream_t stream)
{
  const float* x  = (const float*)d_in[0];
  const float* Wz = (const float*)d_in[1];
  const float* bz = (const float*)d_in[2];
  const float* Wh = (const float*)d_in[3];
  const float* bh = (const float*)d_in[4];

  char* ws = (char*)d_ws;
  unsigned short* xb   = (unsigned short*)(ws);               // 33,554,432
  unsigned short* Wall = (unsigned short*)(ws + 33554432);    //  4,194,304 ([WzT;WhT])
  unsigned short* Pb   = (unsigned short*)(ws + 37748736);    // 33,554,432 (z-preact bf16)
  unsigned short* Qb   = (unsigned short*)(ws + 71303168);    // 33,554,432 (h-preact bf16)
  float* Aagg = (float*)(ws + 104857600);                     //  2,097,152
  float* Bagg = (float*)(ws + 106954752);                     //  2,097,152
  int*   flags = (int*)(ws + 109051904);                      //      2,048
  float* out  = (float*)d_out;

  k_cvt_x<<<M_TOTAL * D_MODEL / 4 / 256, 256, 0, stream>>>(x, xb);
  k_cvt_wT<<<dim3(32, 32, 2), dim3(32, 8), 0, stream>>>(Wz, Wh, Wall, Wall + (size_t)1024 * 1024);
  k_zero_flags<<<1, 256, 0, stream>>>(flags);
  k_gemm8<<<dim3(M_TOTAL / BM, NTOT / BN), 512, 0, stream>>>(xb, Wall, Pb, Qb);
  k_scan_fused<<<BATCH * NCH, 256, 0, stream>>>(Pb, Qb, bz, bh, Aagg, Bagg, flags, out);
}